// Round 7
// baseline (2168.051 us; speedup 1.0000x reference)
//
#include <hip/hip_runtime.h>
#include <hip/hip_bf16.h>

typedef __hip_bfloat16 bf16;
typedef __attribute__((ext_vector_type(8))) short bf16x8;
typedef __attribute__((ext_vector_type(4))) float f32x4;
typedef __attribute__((ext_vector_type(2))) float f32x2;

constexpr int B = 16, CIN = 3, OPL = 32, OC = 96, H = 256, W = 256;
#define EPS 1e-5f

// fraw level offsets (elements)
constexpr size_t FR_L1 = 33554432ull;
constexpr size_t FR_L2 = 41943040ull;
constexpr size_t FR_TOT = 44040192ull;

// ---------------- prep: zero accumulators + convert/pack all weights ----------------
__global__ void k_prep(const float* __restrict__ w0, const float* __restrict__ w1,
                       const float* __restrict__ w2, const float* __restrict__ wf,
                       float* __restrict__ sacc, float* __restrict__ G2zone,
                       bf16* __restrict__ wA, bf16* __restrict__ wbf) {
  int i = blockIdx.x * 256 + threadIdx.x;
  if (i < 3072) sacc[i] = 0.f;
  if (i < 147456 + 1536) G2zone[i] = 0.f;          // G2 + musum
  if (i < OC * OC) wbf[i] = __float2bfloat16(wf[i]);
  if (i < 3 * 5120) {
    int l = i / 5120, rem = i % 5120;
    int entry = rem >> 5, kk = rem & 31;
    int r = entry >> 5, g = (entry >> 4) & 1, lr = entry & 15;
    int t2 = kk >> 4, ic = kk & 15;
    int tap = 2 * r + t2;
    const float* wl = l == 0 ? w0 : (l == 1 ? w1 : w2);
    float v = 0.f;
    if (tap <= 8 && ic < 12) v = wl[((g * 16 + lr) * 12 + ic) * 9 + tap];
    wA[i] = __float2bfloat16(v);
  }
}

// ---------------- avg pool: both levels in one kernel ----------------
// each thread: 4x4 patch of x -> 2x2 of cur1 + 1 of cur2
__global__ void k_avgpool_b(const float* __restrict__ x, float* __restrict__ cur1,
                            float* __restrict__ cur2) {
  int n = B * CIN * 64 * 64;
  int t = blockIdx.x * blockDim.x + threadIdx.x;
  if (t >= n) return;
  int xx = t & 63, y = (t >> 6) & 63, p = t >> 12;
  const float* ip = x + (size_t)p * 65536 + (size_t)(4 * y) * 256 + 4 * xx;
  f32x4 r0 = *(const f32x4*)ip;
  f32x4 r1 = *(const f32x4*)(ip + 256);
  f32x4 r2 = *(const f32x4*)(ip + 512);
  f32x4 r3 = *(const f32x4*)(ip + 768);
  f32x2 c1a, c1b;
  c1a[0] = 0.25f * (r0[0] + r0[1] + r1[0] + r1[1]);
  c1a[1] = 0.25f * (r0[2] + r0[3] + r1[2] + r1[3]);
  c1b[0] = 0.25f * (r2[0] + r2[1] + r3[0] + r3[1]);
  c1b[1] = 0.25f * (r2[2] + r2[3] + r3[2] + r3[3]);
  float* c1p = cur1 + (size_t)p * 16384 + (size_t)(2 * y) * 128 + 2 * xx;
  *(f32x2*)c1p = c1a;
  *(f32x2*)(c1p + 128) = c1b;
  cur2[(size_t)p * 4096 + (size_t)y * 64 + xx] =
      0.25f * (c1a[0] + c1a[1] + c1b[0] + c1b[1]);
}

// ---------------- FUSED: Haar + bilinear-up + conv3x3 (MFMA) + stats, 3 levels ------
__global__ void __launch_bounds__(256) k_fused3m(const float* __restrict__ x,
    const float* __restrict__ cur1, const float* __restrict__ cur2,
    const bf16* __restrict__ wA3,
    const float* __restrict__ b0, const float* __restrict__ b1,
    const float* __restrict__ b2,
    bf16* __restrict__ fraw, float* __restrict__ sacc) {
  __shared__ unsigned int sPool[34 * 34 * 12 + 18 * 18 * 12];
  unsigned int* sInT = sPool;
  float* sCur = (float*)sPool;
  float* sBands = (float*)(sPool + 34 * 34 * 12);

  int bxid = blockIdx.x, b = blockIdx.y;
  int lvl, tile, Hl, ntx;
  const float* cur; const float* bias; bf16* frawL;
  if (bxid < 64)      { lvl = 0; tile = bxid;      Hl = 256; ntx = 8; cur = x;    bias = b0; frawL = fraw; }
  else if (bxid < 80) { lvl = 1; tile = bxid - 64; Hl = 128; ntx = 4; cur = cur1; bias = b1; frawL = fraw + FR_L1; }
  else                { lvl = 2; tile = bxid - 80; Hl = 64;  ntx = 2; cur = cur2; bias = b2; frawL = fraw + FR_L2; }
  const bf16* wA = wA3 + lvl * 5120;
  float* saccL = sacc + lvl * 1024;

  int by = (tile / ntx) * 32, bx = (tile % ntx) * 32;
  int tid = threadIdx.x;
  int h2 = Hl >> 1;
  size_t plane = (size_t)Hl * Hl;

  int w = tid >> 6, l = tid & 63;
  int lr = l & 15, kg = l >> 4;
  int yloc = (w >> 1) * 16, xloc = (w & 1) * 16;
  bf16x8 wf_[5][2];
#pragma unroll
  for (int r = 0; r < 5; r++)
#pragma unroll
    for (int g = 0; g < 2; g++)
      wf_[r][g] = *(const bf16x8*)(wA + ((r * 2 + g) * 16 + lr) * 32 + kg * 8);
  int offr[5];
#pragma unroll
  for (int r = 0; r < 5; r++) {
    int tap = 2 * r + (kg >> 1);
    if (tap > 8) tap = 8;
    int dy = tap / 3 - 1, dx = tap - (tap / 3) * 3 - 1;
    offr[r] = (dy * 34 + dx) * 12 + (kg & 1) * 4;
  }
  float bi[2][4];
#pragma unroll
  for (int g = 0; g < 2; g++)
#pragma unroll
    for (int rg = 0; rg < 4; rg++)
      bi[g][rg] = bias[g * 16 + kg * 4 + rg];

  // phase A: load cur tile, clamped
  const float* cb = cur + (size_t)(b * CIN) * plane;
  for (int it = tid; it < 3 * 36 * 36; it += 256) {
    int xx = it % 36, rest = it / 36, yy = rest % 36, c = rest / 36;
    int gy = by - 2 + yy, gx = bx - 2 + xx;
    gy = gy < 0 ? 0 : (gy > Hl - 1 ? Hl - 1 : gy);
    gx = gx < 0 ? 0 : (gx > Hl - 1 ? Hl - 1 : gx);
    sCur[it] = cb[c * plane + (size_t)gy * Hl + gx];
  }
  __syncthreads();

  // phase B: Haar bands 18x18
  for (int it = tid; it < 18 * 18 * 3; it += 256) {
    int c = it % 3, rest = it / 3, xs = rest % 18, ys = rest / 18;
    const float* cp = sCur + c * 1296 + (2 * ys) * 36 + 2 * xs;
    float e = cp[0], f = cp[1], g = cp[36], h = cp[37];
    f32x4 v;
    v[0] = (e + f + g + h) * 0.5f;
    v[1] = (e + f - g - h) * 0.5f;
    v[2] = (e - f + g - h) * 0.5f;
    v[3] = (e - f - g + h) * 0.5f;
    *(f32x4*)&sBands[(ys * 18 + xs) * 12 + c * 4] = v;
  }
  __syncthreads();

  // phase C: bilinear x2 expand into packed sInT
  int yb_base = (by >> 1) - 1, xb_base = (bx >> 1) - 1;
  for (int it = tid; it < 34 * 34 * 3; it += 256) {
    int c = it % 3, rest = it / 3, xx = rest % 34, yy = rest / 34;
    int base = (yy * 34 + xx) * 12 + c * 2;
    int Y = by - 1 + yy, X = bx - 1 + xx;
    if (Y < 0 || Y >= Hl || X < 0 || X >= Hl) {
      sInT[base] = 0; sInT[base + 1] = 0;
      continue;
    }
    int my = Y >> 1, dy = Y & 1;
    int y0 = my - 1 + dy;
    float wy = dy ? 0.25f : 0.75f;
    int y0c = y0 < 0 ? 0 : y0, y1c = (y0 + 1 > h2 - 1) ? h2 - 1 : y0 + 1;
    int ys0 = y0c - yb_base, ys1 = y1c - yb_base;
    int mx = X >> 1, dx = X & 1;
    int x0 = mx - 1 + dx;
    float wx = dx ? 0.25f : 0.75f;
    int x0c = x0 < 0 ? 0 : x0, x1c = (x0 + 1 > h2 - 1) ? h2 - 1 : x0 + 1;
    int xs0 = x0c - xb_base, xs1 = x1c - xb_base;
    f32x4 c00 = *(const f32x4*)&sBands[(ys0 * 18 + xs0) * 12 + c * 4];
    f32x4 c01 = *(const f32x4*)&sBands[(ys0 * 18 + xs1) * 12 + c * 4];
    f32x4 c10 = *(const f32x4*)&sBands[(ys1 * 18 + xs0) * 12 + c * 4];
    f32x4 c11 = *(const f32x4*)&sBands[(ys1 * 18 + xs1) * 12 + c * 4];
    f32x4 v0 = c00 + wx * (c01 - c00);
    f32x4 v1 = c10 + wx * (c11 - c10);
    f32x4 v = v0 + wy * (v1 - v0);
    unsigned int d0 = (unsigned int)__bfloat16_as_ushort(__float2bfloat16(v[0]))
                    | ((unsigned int)__bfloat16_as_ushort(__float2bfloat16(v[1])) << 16);
    unsigned int d1 = (unsigned int)__bfloat16_as_ushort(__float2bfloat16(v[2]))
                    | ((unsigned int)__bfloat16_as_ushort(__float2bfloat16(v[3])) << 16);
    sInT[base] = d0;
    sInT[base + 1] = d1;
  }
  for (int it = tid; it < 34 * 34; it += 256) {
    sInT[it * 12 + 6] = 0;
    sInT[it * 12 + 7] = 0;
  }
  __syncthreads();

  // MFMA conv + bf16 store + fused stats
  float s_[2][4], s2_[2][4];
#pragma unroll
  for (int g = 0; g < 2; g++)
#pragma unroll
    for (int rg = 0; rg < 4; rg++) { s_[g][rg] = 0.f; s2_[g][rg] = 0.f; }

  bf16* frb = frawL + (size_t)b * OPL * plane;
  for (int y = 0; y < 16; y++) {
    int rowbase = ((yloc + y + 1) * 34 + (xloc + lr + 1)) * 12;
    f32x4 a0 = {0, 0, 0, 0}, a1 = {0, 0, 0, 0};
#pragma unroll
    for (int r = 0; r < 5; r++) {
      bf16x8 bf_ = *(const bf16x8*)&sInT[rowbase + offr[r]];
      a0 = __builtin_amdgcn_mfma_f32_16x16x32_bf16(wf_[r][0], bf_, a0, 0, 0, 0);
      a1 = __builtin_amdgcn_mfma_f32_16x16x32_bf16(wf_[r][1], bf_, a1, 0, 0, 0);
    }
    int gy = by + yloc + y, gxp = bx + xloc + lr;
    size_t po = (size_t)gy * Hl + gxp;
#pragma unroll
    for (int rg = 0; rg < 4; rg++) {
      bf16 vb0 = __float2bfloat16(a0[rg] + bi[0][rg]);
      bf16 vb1 = __float2bfloat16(a1[rg] + bi[1][rg]);
      frb[(size_t)(kg * 4 + rg) * plane + po] = vb0;
      frb[(size_t)(16 + kg * 4 + rg) * plane + po] = vb1;
      float v0 = __bfloat162float(vb0), v1 = __bfloat162float(vb1);
      s_[0][rg] += v0; s2_[0][rg] += v0 * v0;
      s_[1][rg] += v1; s2_[1][rg] += v1 * v1;
    }
  }
#pragma unroll
  for (int g = 0; g < 2; g++)
#pragma unroll
    for (int rg = 0; rg < 4; rg++) {
      float s = s_[g][rg], s2 = s2_[g][rg];
#pragma unroll
      for (int m = 8; m >= 1; m >>= 1) {
        s += __shfl_xor(s, m);
        s2 += __shfl_xor(s2, m);
      }
      if (lr == 0) {
        int pc = b * OPL + g * 16 + kg * 4 + rg;
        atomicAdd(&saccL[pc * 2], s);
        atomicAdd(&saccL[pc * 2 + 1], s2);
      }
    }
}

// ---------------- shared transform: 8 px of channel ch at row y, cols x0..x0+7 ------
__device__ inline void cat_row8(const bf16* __restrict__ fraw,
    const float* __restrict__ sacc, const float* __restrict__ a0,
    const float* __restrict__ a1, const float* __restrict__ a2,
    int b, int ch, int y, int x0, bf16x8* out8) {
  int lvl = ch < 32 ? 0 : (ch < 64 ? 1 : 2);
  int cl = ch - 32 * lvl;
  int pcl = b * 32 + cl;
  const float* sl = sacc + lvl * 1024;
  float invN = lvl == 0 ? (1.f / 65536.f) : (lvl == 1 ? (1.f / 16384.f) : (1.f / 4096.f));
  float mean = sl[pcl * 2] * invN;
  float var = sl[pcl * 2 + 1] * invN - mean * mean;
  float rstd = rsqrtf(fmaxf(var, 0.f) + EPS);
  float al = lvl == 0 ? a0[0] : (lvl == 1 ? a1[0] : a2[0]);
  bf16x8 o;
  if (lvl == 0) {
    bf16x8 in = *(const bf16x8*)(fraw + (((size_t)pcl) << 16) + y * 256 + x0);
#pragma unroll
    for (int j = 0; j < 8; j++) {
      float v = __bfloat162float(__ushort_as_bfloat16((unsigned short)in[j]));
      v = (v - mean) * rstd;
      v = v >= 0.f ? v : al * v;
      o[j] = (short)__bfloat16_as_ushort(__float2bfloat16(v));
    }
  } else {
    int n = lvl == 1 ? 128 : 64;
    size_t lvloff = lvl == 1 ? FR_L1 : FR_L2;
    int shift = lvl == 1 ? 14 : 12;
    const bf16* ip = fraw + lvloff + (((size_t)pcl) << shift);
    int y0; float wy;
    if (lvl == 1) { int d = y & 1; y0 = (y >> 1) - 1 + d; wy = d ? 0.25f : 0.75f; }
    else {
      int d = y & 3; y0 = (y >> 2) - 1 + (d >> 1);
      wy = (d & 1) ? ((d >> 1) ? 0.375f : 0.875f) : ((d >> 1) ? 0.125f : 0.625f);
    }
    int y0c = y0 < 0 ? 0 : y0;
    int y1c = (y0 + 1 > n - 1) ? n - 1 : y0 + 1;
    const bf16* r0p = ip + (size_t)y0c * n;
    const bf16* r1p = ip + (size_t)y1c * n;
#pragma unroll
    for (int j = 0; j < 8; j++) {
      int xx = x0 + j;
      int xi; float wx;
      if (lvl == 1) { int d = xx & 1; xi = (xx >> 1) - 1 + d; wx = d ? 0.25f : 0.75f; }
      else {
        int d = xx & 3; xi = (xx >> 2) - 1 + (d >> 1);
        wx = (d & 1) ? ((d >> 1) ? 0.375f : 0.875f) : ((d >> 1) ? 0.125f : 0.625f);
      }
      int x0c = xi < 0 ? 0 : xi;
      int x1c = (xi + 1 > n - 1) ? n - 1 : xi + 1;
      float v00 = __bfloat162float(r0p[x0c]);
      float v01 = __bfloat162float(r0p[x1c]);
      float v10 = __bfloat162float(r1p[x0c]);
      float v11 = __bfloat162float(r1p[x1c]);
      v00 = (v00 - mean) * rstd; v00 = v00 >= 0.f ? v00 : al * v00;
      v01 = (v01 - mean) * rstd; v01 = v01 >= 0.f ? v01 : al * v01;
      v10 = (v10 - mean) * rstd; v10 = v10 >= 0.f ? v10 : al * v10;
      v11 = (v11 - mean) * rstd; v11 = v11 >= 0.f ? v11 : al * v11;
      float v = (1.f - wy) * ((1.f - wx) * v00 + wx * v01)
              + wy * ((1.f - wx) * v10 + wx * v11);
      o[j] = (short)__bfloat16_as_ushort(__float2bfloat16(v));
    }
  }
  *out8 = o;
}

// ---------------- moments from fraw (cat-free): G2 = cat*cat^T, musum ---------------
// grid: 16 b x 32 chunks (2048 px); 384 thr. LDS tile 96 ch x 256 px, stride 264.
__global__ void __launch_bounds__(384) k_moments2(const bf16* __restrict__ fraw,
    const float* __restrict__ sacc, const float* __restrict__ a0,
    const float* __restrict__ a1, const float* __restrict__ a2,
    float* __restrict__ G2, float* __restrict__ musum) {
  __shared__ short sV[96 * 264];
  int b = blockIdx.x >> 5, chunk = blockIdx.x & 31;
  int tid = threadIdx.x;
  int ti = tid >> 6, l = tid & 63, lr = l & 15, kg = l >> 4;
  f32x4 acc0 = {0,0,0,0}, acc1 = {0,0,0,0}, acc2 = {0,0,0,0};
  f32x4 acc3 = {0,0,0,0}, acc4 = {0,0,0,0}, acc5 = {0,0,0,0};
  f32x4 accO = {0,0,0,0};
  bf16x8 ones;
#pragma unroll
  for (int j = 0; j < 8; j++) ones[j] = (short)0x3F80;

  for (int sub = 0; sub < 8; sub++) {
    int y = chunk * 8 + sub;
    __syncthreads();
    // stage-transform 96 x 256
#pragma unroll
    for (int a = 0; a < 8; a++) {
      int u = tid + a * 384;
      int ch = u % 96, grp = u / 96;
      int px0 = grp * 8;
      bf16x8 o8;
      cat_row8(fraw, sacc, a0, a1, a2, b, ch, y, px0, &o8);
      *(bf16x8*)&sV[ch * 264 + px0] = o8;
    }
    __syncthreads();
    // MFMA over 8 K-steps of 32 px
#pragma unroll
    for (int s = 0; s < 8; s++) {
      int po = s * 32 + kg * 8;
      bf16x8 fa = *(const bf16x8*)&sV[(ti * 16 + lr) * 264 + po];
      bf16x8 f0 = *(const bf16x8*)&sV[(0 * 16 + lr) * 264 + po];
      bf16x8 f1 = *(const bf16x8*)&sV[(1 * 16 + lr) * 264 + po];
      bf16x8 f2 = *(const bf16x8*)&sV[(2 * 16 + lr) * 264 + po];
      bf16x8 f3 = *(const bf16x8*)&sV[(3 * 16 + lr) * 264 + po];
      bf16x8 f4 = *(const bf16x8*)&sV[(4 * 16 + lr) * 264 + po];
      bf16x8 f5 = *(const bf16x8*)&sV[(5 * 16 + lr) * 264 + po];
      acc0 = __builtin_amdgcn_mfma_f32_16x16x32_bf16(fa, f0, acc0, 0, 0, 0);
      acc1 = __builtin_amdgcn_mfma_f32_16x16x32_bf16(fa, f1, acc1, 0, 0, 0);
      acc2 = __builtin_amdgcn_mfma_f32_16x16x32_bf16(fa, f2, acc2, 0, 0, 0);
      acc3 = __builtin_amdgcn_mfma_f32_16x16x32_bf16(fa, f3, acc3, 0, 0, 0);
      acc4 = __builtin_amdgcn_mfma_f32_16x16x32_bf16(fa, f4, acc4, 0, 0, 0);
      acc5 = __builtin_amdgcn_mfma_f32_16x16x32_bf16(fa, f5, acc5, 0, 0, 0);
      accO = __builtin_amdgcn_mfma_f32_16x16x32_bf16(fa, ones, accO, 0, 0, 0);
    }
  }
  f32x4 accs[6] = {acc0, acc1, acc2, acc3, acc4, acc5};
#pragma unroll
  for (int t = 0; t < 6; t++)
#pragma unroll
    for (int r = 0; r < 4; r++) {
      int i = ti * 16 + kg * 4 + r, j = t * 16 + lr;
      atomicAdd(&G2[(size_t)(b * OC + i) * OC + j], accs[t][r]);
    }
#pragma unroll
  for (int r = 0; r < 4; r++) {
    int i = ti * 16 + kg * 4 + r;
    if (lr == 0) atomicAdd(&musum[b * OC + i], accO[r]);
  }
}

// ---------------- combine: per (b,oc) scale/shift for fused IN ----------------
__global__ void __launch_bounds__(128) k_statsF(const float* __restrict__ G2,
    const float* __restrict__ musum, const float* __restrict__ wf,
    const float* __restrict__ bfv, float* __restrict__ scale,
    float* __restrict__ shift) {
  int oc = blockIdx.x, b = blockIdx.y;
  int j = threadIdx.x;
  float quad = 0.f, lin = 0.f;
  if (j < OC) {
    float wj = __bfloat162float(__float2bfloat16(wf[oc * OC + j]));
    const float* g = G2 + (size_t)(b * OC) * OC + j;
    float inner = 0.f;
#pragma unroll 4
    for (int i = 0; i < OC; i++) {
      float wi = __bfloat162float(__float2bfloat16(wf[oc * OC + i]));
      inner = fmaf(wi, g[(size_t)i * OC], inner);
    }
    quad = wj * inner;
    lin = wj * musum[b * OC + j];
  }
  __shared__ float rq[2], rl[2];
  for (int off = 32; off > 0; off >>= 1) {
    quad += __shfl_down(quad, off);
    lin += __shfl_down(lin, off);
  }
  if ((threadIdx.x & 63) == 0) { rq[threadIdx.x >> 6] = quad; rl[threadIdx.x >> 6] = lin; }
  __syncthreads();
  if (threadIdx.x == 0) {
    float Q = rq[0] + rq[1], L = rl[0] + rl[1];
    const float invN = 1.f / 65536.f;
    float bias = bfv[oc];
    float mean = L * invN + bias;
    float e2 = Q * invN + 2.f * bias * (L * invN) + bias * bias;
    float var = e2 - mean * mean;
    float rstd = rsqrtf(fmaxf(var, 0.f) + EPS);
    scale[b * OC + oc] = rstd;
    shift[b * OC + oc] = (bias - mean) * rstd;
  }
}

// ---------------- final conv1x1 (MFMA) + IN + prelu from fraw (cat-free) ------------
constexpr int CROW = 52;
__global__ void __launch_bounds__(256) k_conv1x1g(const bf16* __restrict__ fraw,
    const float* __restrict__ sacc, const float* __restrict__ a0,
    const float* __restrict__ a1, const float* __restrict__ a2,
    const bf16* __restrict__ wbf, const float* __restrict__ scale,
    const float* __restrict__ shift, const float* __restrict__ af,
    float* __restrict__ out) {
  __shared__ unsigned int sT[128 * CROW];
  int b = blockIdx.x >> 6;
  int px0 = (blockIdx.x & 63) * 1024;
  int tid = threadIdx.x, w = tid >> 6, l = tid & 63;
  int lr = l & 15, kg = l >> 4;
  bf16x8 wf_[6][3];
#pragma unroll
  for (int t = 0; t < 6; t++)
#pragma unroll
    for (int ks = 0; ks < 3; ks++)
      wf_[t][ks] = *(const bf16x8*)(wbf + (t * 16 + lr) * OC + ks * 32 + kg * 8);
  float al = af[0];
  int bo = b * OC;
  const f32x4* scv = (const f32x4*)(scale + bo);
  const f32x4* shv = (const f32x4*)(shift + bo);

  for (int round = 0; round < 8; round++) {
    int rp0 = px0 + round * 128;
    __syncthreads();
    // stage-transform 128 px x 96 ic (pair-packed)
#pragma unroll
    for (int a = 0; a < 3; a++) {
      int u = tid + a * 256;
      int icd = u % 48, grp = u / 48;
      int lpx0 = grp * 8;
      int gpx = rp0 + lpx0;
      int y = gpx >> 8, x0 = gpx & 255;
      bf16x8 oA, oB;
      cat_row8(fraw, sacc, a0, a1, a2, b, 2 * icd, y, x0, &oA);
      cat_row8(fraw, sacc, a0, a1, a2, b, 2 * icd + 1, y, x0, &oB);
#pragma unroll
      for (int j = 0; j < 8; j++) {
        unsigned int d = (unsigned int)(unsigned short)oA[j]
                       | ((unsigned int)(unsigned short)oB[j] << 16);
        sT[(lpx0 + j) * CROW + icd] = d;
      }
    }
    __syncthreads();
#pragma unroll
    for (int pt = 0; pt < 2; pt++) {
      int tloc = w * 2 + pt;
      int pl = tloc * 16 + lr;
      f32x4 a0_ = {0,0,0,0}, a1_ = {0,0,0,0}, a2_ = {0,0,0,0};
      f32x4 a3_ = {0,0,0,0}, a4_ = {0,0,0,0}, a5_ = {0,0,0,0};
#pragma unroll
      for (int ks = 0; ks < 3; ks++) {
        bf16x8 bf_ = *(const bf16x8*)&sT[pl * CROW + ks * 16 + kg * 4];
        a0_ = __builtin_amdgcn_mfma_f32_16x16x32_bf16(wf_[0][ks], bf_, a0_, 0, 0, 0);
        a1_ = __builtin_amdgcn_mfma_f32_16x16x32_bf16(wf_[1][ks], bf_, a1_, 0, 0, 0);
        a2_ = __builtin_amdgcn_mfma_f32_16x16x32_bf16(wf_[2][ks], bf_, a2_, 0, 0, 0);
        a3_ = __builtin_amdgcn_mfma_f32_16x16x32_bf16(wf_[3][ks], bf_, a3_, 0, 0, 0);
        a4_ = __builtin_amdgcn_mfma_f32_16x16x32_bf16(wf_[4][ks], bf_, a4_, 0, 0, 0);
        a5_ = __builtin_amdgcn_mfma_f32_16x16x32_bf16(wf_[5][ks], bf_, a5_, 0, 0, 0);
      }
      f32x4 accs[6] = {a0_, a1_, a2_, a3_, a4_, a5_};
      int px = rp0 + tloc * 16 + lr;
#pragma unroll
      for (int t = 0; t < 6; t++) {
        f32x4 sc4 = scv[t * 4 + kg];
        f32x4 sh4 = shv[t * 4 + kg];
#pragma unroll
        for (int r = 0; r < 4; r++) {
          int oc = t * 16 + kg * 4 + r;
          float v = accs[t][r] * sc4[r] + sh4[r];
          v = v >= 0.f ? v : al * v;
          out[((size_t)(bo + oc) << 16) + px] = v;
        }
      }
    }
  }
}

extern "C" void kernel_launch(void* const* d_in, const int* in_sizes, int n_in,
                              void* d_out, int out_size, void* d_ws, size_t ws_size,
                              hipStream_t stream) {
  const float* x   = (const float*)d_in[0];
  const float* w[3]  = {(const float*)d_in[1], (const float*)d_in[4], (const float*)d_in[7]};
  const float* bb[3] = {(const float*)d_in[2], (const float*)d_in[5], (const float*)d_in[8]};
  const float* aa[3] = {(const float*)d_in[3], (const float*)d_in[6], (const float*)d_in[9]};
  const float* wfp = (const float*)d_in[10];
  const float* bfv = (const float*)d_in[11];
  const float* af  = (const float*)d_in[12];
  float* out = (float*)d_out;

  // workspace: fraw bf16 88 MB | cur1 | cur2 | sacc | wA3 | G2 | musum | scale | shift | wbf
  char* ws = (char*)d_ws;
  bf16*  fraw = (bf16*)ws;
  float* cur1 = (float*)(ws + FR_TOT * 2ull);
  float* cur2 = cur1 + 786432;
  float* sacc = cur2 + 196608;
  bf16*  wA3  = (bf16*)(sacc + 3072);
  float* G2   = (float*)(wA3 + 15360);
  float* musum = G2 + 147456;
  float* scale = musum + 1536;
  float* shift = scale + 1536;
  bf16*  wbf   = (bf16*)(shift + 1536);

  auto cdiv = [](int a, int b) { return (a + b - 1) / b; };

  k_prep<<<582, 256, 0, stream>>>(w[0], w[1], w[2], wfp, sacc, G2, wA3, wbf);
  k_avgpool_b<<<cdiv(B * CIN * 64 * 64, 256), 256, 0, stream>>>(x, cur1, cur2);

  dim3 g3(84, B);
  k_fused3m<<<g3, 256, 0, stream>>>(x, cur1, cur2, wA3, bb[0], bb[1], bb[2],
                                    fraw, sacc);
  k_moments2<<<16 * 32, 384, 0, stream>>>(fraw, sacc, aa[0], aa[1], aa[2], G2, musum);
  dim3 gs(OC, B);
  k_statsF<<<gs, 128, 0, stream>>>(G2, musum, wfp, bfv, scale, shift);
  k_conv1x1g<<<16 * 64, 256, 0, stream>>>(fraw, sacc, aa[0], aa[1], aa[2], wbf,
                                          scale, shift, af, out);
}

// Round 8
// 611.780 us; speedup vs baseline: 3.5438x; 3.5438x over previous
//
#include <hip/hip_runtime.h>
#include <hip/hip_bf16.h>

typedef __hip_bfloat16 bf16;
typedef __attribute__((ext_vector_type(8))) short bf16x8;
typedef __attribute__((ext_vector_type(4))) float f32x4;
typedef __attribute__((ext_vector_type(2))) float f32x2;

constexpr int B = 16, CIN = 3, OPL = 32, OC = 96, H = 256, W = 256;
#define EPS 1e-5f

// fraw level offsets (elements)
constexpr size_t FR_L1 = 33554432ull;
constexpr size_t FR_L2 = 41943040ull;
constexpr size_t FR_TOT = 44040192ull;

// ---------------- prep: zero accumulators + convert/pack all weights ----------------
__global__ void k_prep(const float* __restrict__ w0, const float* __restrict__ w1,
                       const float* __restrict__ w2, const float* __restrict__ wf,
                       float* __restrict__ sacc, float* __restrict__ G2zone,
                       bf16* __restrict__ wA, bf16* __restrict__ wbf) {
  int i = blockIdx.x * 256 + threadIdx.x;
  if (i < 3072) sacc[i] = 0.f;
  if (i < 147456 + 1536) G2zone[i] = 0.f;          // G2 + musum
  if (i < OC * OC) wbf[i] = __float2bfloat16(wf[i]);
  if (i < 3 * 5120) {
    int l = i / 5120, rem = i % 5120;
    int entry = rem >> 5, kk = rem & 31;
    int r = entry >> 5, g = (entry >> 4) & 1, lr = entry & 15;
    int t2 = kk >> 4, ic = kk & 15;
    int tap = 2 * r + t2;
    const float* wl = l == 0 ? w0 : (l == 1 ? w1 : w2);
    float v = 0.f;
    if (tap <= 8 && ic < 12) v = wl[((g * 16 + lr) * 12 + ic) * 9 + tap];
    wA[i] = __float2bfloat16(v);
  }
}

// ---------------- avg pool: both levels in one kernel ----------------
__global__ void k_avgpool_b(const float* __restrict__ x, float* __restrict__ cur1,
                            float* __restrict__ cur2) {
  int n = B * CIN * 64 * 64;
  int t = blockIdx.x * blockDim.x + threadIdx.x;
  if (t >= n) return;
  int xx = t & 63, y = (t >> 6) & 63, p = t >> 12;
  const float* ip = x + (size_t)p * 65536 + (size_t)(4 * y) * 256 + 4 * xx;
  f32x4 r0 = *(const f32x4*)ip;
  f32x4 r1 = *(const f32x4*)(ip + 256);
  f32x4 r2 = *(const f32x4*)(ip + 512);
  f32x4 r3 = *(const f32x4*)(ip + 768);
  f32x2 c1a, c1b;
  c1a[0] = 0.25f * (r0[0] + r0[1] + r1[0] + r1[1]);
  c1a[1] = 0.25f * (r0[2] + r0[3] + r1[2] + r1[3]);
  c1b[0] = 0.25f * (r2[0] + r2[1] + r3[0] + r3[1]);
  c1b[1] = 0.25f * (r2[2] + r2[3] + r3[2] + r3[3]);
  float* c1p = cur1 + (size_t)p * 16384 + (size_t)(2 * y) * 128 + 2 * xx;
  *(f32x2*)c1p = c1a;
  *(f32x2*)(c1p + 128) = c1b;
  cur2[(size_t)p * 4096 + (size_t)y * 64 + xx] =
      0.25f * (c1a[0] + c1a[1] + c1b[0] + c1b[1]);
}

// ---------------- FUSED: Haar + bilinear-up + conv3x3 (MFMA) + stats, 3 levels ------
__global__ void __launch_bounds__(256) k_fused3m(const float* __restrict__ x,
    const float* __restrict__ cur1, const float* __restrict__ cur2,
    const bf16* __restrict__ wA3,
    const float* __restrict__ b0, const float* __restrict__ b1,
    const float* __restrict__ b2,
    bf16* __restrict__ fraw, float* __restrict__ sacc) {
  __shared__ unsigned int sPool[34 * 34 * 12 + 18 * 18 * 12];
  unsigned int* sInT = sPool;
  float* sCur = (float*)sPool;
  float* sBands = (float*)(sPool + 34 * 34 * 12);

  int bxid = blockIdx.x, b = blockIdx.y;
  int lvl, tile, Hl, ntx;
  const float* cur; const float* bias; bf16* frawL;
  if (bxid < 64)      { lvl = 0; tile = bxid;      Hl = 256; ntx = 8; cur = x;    bias = b0; frawL = fraw; }
  else if (bxid < 80) { lvl = 1; tile = bxid - 64; Hl = 128; ntx = 4; cur = cur1; bias = b1; frawL = fraw + FR_L1; }
  else                { lvl = 2; tile = bxid - 80; Hl = 64;  ntx = 2; cur = cur2; bias = b2; frawL = fraw + FR_L2; }
  const bf16* wA = wA3 + lvl * 5120;
  float* saccL = sacc + lvl * 1024;

  int by = (tile / ntx) * 32, bx = (tile % ntx) * 32;
  int tid = threadIdx.x;
  int h2 = Hl >> 1;
  size_t plane = (size_t)Hl * Hl;

  int w = tid >> 6, l = tid & 63;
  int lr = l & 15, kg = l >> 4;
  int yloc = (w >> 1) * 16, xloc = (w & 1) * 16;
  bf16x8 wf_[5][2];
#pragma unroll
  for (int r = 0; r < 5; r++)
#pragma unroll
    for (int g = 0; g < 2; g++)
      wf_[r][g] = *(const bf16x8*)(wA + ((r * 2 + g) * 16 + lr) * 32 + kg * 8);
  int offr[5];
#pragma unroll
  for (int r = 0; r < 5; r++) {
    int tap = 2 * r + (kg >> 1);
    if (tap > 8) tap = 8;
    int dy = tap / 3 - 1, dx = tap - (tap / 3) * 3 - 1;
    offr[r] = (dy * 34 + dx) * 12 + (kg & 1) * 4;
  }
  float bi[2][4];
#pragma unroll
  for (int g = 0; g < 2; g++)
#pragma unroll
    for (int rg = 0; rg < 4; rg++)
      bi[g][rg] = bias[g * 16 + kg * 4 + rg];

  // phase A: load cur tile, clamped
  const float* cb = cur + (size_t)(b * CIN) * plane;
  for (int it = tid; it < 3 * 36 * 36; it += 256) {
    int xx = it % 36, rest = it / 36, yy = rest % 36, c = rest / 36;
    int gy = by - 2 + yy, gx = bx - 2 + xx;
    gy = gy < 0 ? 0 : (gy > Hl - 1 ? Hl - 1 : gy);
    gx = gx < 0 ? 0 : (gx > Hl - 1 ? Hl - 1 : gx);
    sCur[it] = cb[c * plane + (size_t)gy * Hl + gx];
  }
  __syncthreads();

  // phase B: Haar bands 18x18
  for (int it = tid; it < 18 * 18 * 3; it += 256) {
    int c = it % 3, rest = it / 3, xs = rest % 18, ys = rest / 18;
    const float* cp = sCur + c * 1296 + (2 * ys) * 36 + 2 * xs;
    float e = cp[0], f = cp[1], g = cp[36], h = cp[37];
    f32x4 v;
    v[0] = (e + f + g + h) * 0.5f;
    v[1] = (e + f - g - h) * 0.5f;
    v[2] = (e - f + g - h) * 0.5f;
    v[3] = (e - f - g + h) * 0.5f;
    *(f32x4*)&sBands[(ys * 18 + xs) * 12 + c * 4] = v;
  }
  __syncthreads();

  // phase C: bilinear x2 expand into packed sInT
  int yb_base = (by >> 1) - 1, xb_base = (bx >> 1) - 1;
  for (int it = tid; it < 34 * 34 * 3; it += 256) {
    int c = it % 3, rest = it / 3, xx = rest % 34, yy = rest / 34;
    int base = (yy * 34 + xx) * 12 + c * 2;
    int Y = by - 1 + yy, X = bx - 1 + xx;
    if (Y < 0 || Y >= Hl || X < 0 || X >= Hl) {
      sInT[base] = 0; sInT[base + 1] = 0;
      continue;
    }
    int my = Y >> 1, dy = Y & 1;
    int y0 = my - 1 + dy;
    float wy = dy ? 0.25f : 0.75f;
    int y0c = y0 < 0 ? 0 : y0, y1c = (y0 + 1 > h2 - 1) ? h2 - 1 : y0 + 1;
    int ys0 = y0c - yb_base, ys1 = y1c - yb_base;
    int mx = X >> 1, dx = X & 1;
    int x0 = mx - 1 + dx;
    float wx = dx ? 0.25f : 0.75f;
    int x0c = x0 < 0 ? 0 : x0, x1c = (x0 + 1 > h2 - 1) ? h2 - 1 : x0 + 1;
    int xs0 = x0c - xb_base, xs1 = x1c - xb_base;
    f32x4 c00 = *(const f32x4*)&sBands[(ys0 * 18 + xs0) * 12 + c * 4];
    f32x4 c01 = *(const f32x4*)&sBands[(ys0 * 18 + xs1) * 12 + c * 4];
    f32x4 c10 = *(const f32x4*)&sBands[(ys1 * 18 + xs0) * 12 + c * 4];
    f32x4 c11 = *(const f32x4*)&sBands[(ys1 * 18 + xs1) * 12 + c * 4];
    f32x4 v0 = c00 + wx * (c01 - c00);
    f32x4 v1 = c10 + wx * (c11 - c10);
    f32x4 v = v0 + wy * (v1 - v0);
    unsigned int d0 = (unsigned int)__bfloat16_as_ushort(__float2bfloat16(v[0]))
                    | ((unsigned int)__bfloat16_as_ushort(__float2bfloat16(v[1])) << 16);
    unsigned int d1 = (unsigned int)__bfloat16_as_ushort(__float2bfloat16(v[2]))
                    | ((unsigned int)__bfloat16_as_ushort(__float2bfloat16(v[3])) << 16);
    sInT[base] = d0;
    sInT[base + 1] = d1;
  }
  for (int it = tid; it < 34 * 34; it += 256) {
    sInT[it * 12 + 6] = 0;
    sInT[it * 12 + 7] = 0;
  }
  __syncthreads();

  // MFMA conv + bf16 store + fused stats
  float s_[2][4], s2_[2][4];
#pragma unroll
  for (int g = 0; g < 2; g++)
#pragma unroll
    for (int rg = 0; rg < 4; rg++) { s_[g][rg] = 0.f; s2_[g][rg] = 0.f; }

  bf16* frb = frawL + (size_t)b * OPL * plane;
  for (int y = 0; y < 16; y++) {
    int rowbase = ((yloc + y + 1) * 34 + (xloc + lr + 1)) * 12;
    f32x4 a0 = {0, 0, 0, 0}, a1 = {0, 0, 0, 0};
#pragma unroll
    for (int r = 0; r < 5; r++) {
      bf16x8 bf_ = *(const bf16x8*)&sInT[rowbase + offr[r]];
      a0 = __builtin_amdgcn_mfma_f32_16x16x32_bf16(wf_[r][0], bf_, a0, 0, 0, 0);
      a1 = __builtin_amdgcn_mfma_f32_16x16x32_bf16(wf_[r][1], bf_, a1, 0, 0, 0);
    }
    int gy = by + yloc + y, gxp = bx + xloc + lr;
    size_t po = (size_t)gy * Hl + gxp;
#pragma unroll
    for (int rg = 0; rg < 4; rg++) {
      bf16 vb0 = __float2bfloat16(a0[rg] + bi[0][rg]);
      bf16 vb1 = __float2bfloat16(a1[rg] + bi[1][rg]);
      frb[(size_t)(kg * 4 + rg) * plane + po] = vb0;
      frb[(size_t)(16 + kg * 4 + rg) * plane + po] = vb1;
      float v0 = __bfloat162float(vb0), v1 = __bfloat162float(vb1);
      s_[0][rg] += v0; s2_[0][rg] += v0 * v0;
      s_[1][rg] += v1; s2_[1][rg] += v1 * v1;
    }
  }
#pragma unroll
  for (int g = 0; g < 2; g++)
#pragma unroll
    for (int rg = 0; rg < 4; rg++) {
      float s = s_[g][rg], s2 = s2_[g][rg];
#pragma unroll
      for (int m = 8; m >= 1; m >>= 1) {
        s += __shfl_xor(s, m);
        s2 += __shfl_xor(s2, m);
      }
      if (lr == 0) {
        int pc = b * OPL + g * 16 + kg * 4 + rg;
        atomicAdd(&saccL[pc * 2], s);
        atomicAdd(&saccL[pc * 2 + 1], s2);
      }
    }
}

// ---------------- all levels: normalize + prelu (+ bilinear up) -> cat, 8 px/thread -
__global__ void __launch_bounds__(256) k_normcat(const bf16* __restrict__ fraw,
    const float* __restrict__ sacc, const float* __restrict__ a0,
    const float* __restrict__ a1, const float* __restrict__ a2,
    bf16* __restrict__ cat) {
  int t = blockIdx.x * 256 + threadIdx.x;
  if (t >= B * OC * H * W / 8) return;
  int pc96 = t >> 13;
  int b = pc96 / OC, c = pc96 - b * OC;
  int tloc = t & 8191;
  bf16x8 o;
  if (c < 32) {
    int pcl = b * 32 + c;
    const float invN = 1.f / 65536.f;
    float mean = sacc[pcl * 2] * invN;
    float var = sacc[pcl * 2 + 1] * invN - mean * mean;
    float rstd = rsqrtf(fmaxf(var, 0.f) + EPS);
    float al = a0[0];
    bf16x8 in = *(const bf16x8*)(fraw + (((size_t)pcl) << 16) + tloc * 8);
#pragma unroll
    for (int j = 0; j < 8; j++) {
      float v = __bfloat162float(__ushort_as_bfloat16((unsigned short)in[j]));
      v = (v - mean) * rstd;
      v = v >= 0.f ? v : al * v;
      o[j] = (short)__bfloat16_as_ushort(__float2bfloat16(v));
    }
  } else {
    int lvl = c < 64 ? 1 : 2;
    int cl = c - 32 * lvl;
    int pcl = b * 32 + cl;
    int n = (lvl == 1) ? 128 : 64;
    int shift = (lvl == 1) ? 14 : 12;
    size_t lvloff = (lvl == 1) ? FR_L1 : FR_L2;
    const float* sl = sacc + lvl * 1024;
    float invN = 1.f / (float)(n * n);
    float mean = sl[pcl * 2] * invN;
    float var = sl[pcl * 2 + 1] * invN - mean * mean;
    float rstd = rsqrtf(fmaxf(var, 0.f) + EPS);
    float al = (lvl == 1) ? a1[0] : a2[0];
    const bf16* ip = fraw + lvloff + (((size_t)pcl) << shift);
    int X0 = (tloc & 31) * 8, y = tloc >> 5;
    int y0; float wy;
    if (lvl == 1) { int d = y & 1; y0 = (y >> 1) - 1 + d; wy = d ? 0.25f : 0.75f; }
    else {
      int d = y & 3; y0 = (y >> 2) - 1 + (d >> 1);
      wy = (d & 1) ? ((d >> 1) ? 0.375f : 0.875f) : ((d >> 1) ? 0.125f : 0.625f);
    }
    int y0c = y0 < 0 ? 0 : y0;
    int y1c = (y0 + 1 > n - 1) ? n - 1 : y0 + 1;
    const bf16* r0p = ip + (size_t)y0c * n;
    const bf16* r1p = ip + (size_t)y1c * n;
#pragma unroll
    for (int j = 0; j < 8; j++) {
      int x = X0 + j;
      int x0; float wx;
      if (lvl == 1) { int d = x & 1; x0 = (x >> 1) - 1 + d; wx = d ? 0.25f : 0.75f; }
      else {
        int d = x & 3; x0 = (x >> 2) - 1 + (d >> 1);
        wx = (d & 1) ? ((d >> 1) ? 0.375f : 0.875f) : ((d >> 1) ? 0.125f : 0.625f);
      }
      int x0c = x0 < 0 ? 0 : x0;
      int x1c = (x0 + 1 > n - 1) ? n - 1 : x0 + 1;
      float v00 = __bfloat162float(r0p[x0c]);
      float v01 = __bfloat162float(r0p[x1c]);
      float v10 = __bfloat162float(r1p[x0c]);
      float v11 = __bfloat162float(r1p[x1c]);
      v00 = (v00 - mean) * rstd; v00 = v00 >= 0.f ? v00 : al * v00;
      v01 = (v01 - mean) * rstd; v01 = v01 >= 0.f ? v01 : al * v01;
      v10 = (v10 - mean) * rstd; v10 = v10 >= 0.f ? v10 : al * v10;
      v11 = (v11 - mean) * rstd; v11 = v11 >= 0.f ? v11 : al * v11;
      float v = (1.f - wy) * ((1.f - wx) * v00 + wx * v01)
              + wy * ((1.f - wx) * v10 + wx * v11);
      o[j] = (short)__bfloat16_as_ushort(__float2bfloat16(v));
    }
  }
  *(bf16x8*)(cat + (((size_t)pc96) << 16) + tloc * 8) = o;
}

// ---------------- second moments of cat per batch: G2 = cat*cat^T, musum ----------------
__global__ void __launch_bounds__(384) k_moments(const bf16* __restrict__ cat,
    float* __restrict__ G2, float* __restrict__ musum) {
  int b = blockIdx.x >> 5;
  int chunk = blockIdx.x & 31;
  int ti = threadIdx.x >> 6;
  int l = threadIdx.x & 63;
  int lr = l & 15, kg = l >> 4;
  const bf16* base = cat + ((size_t)(b * OC) << 16);
  f32x4 acc0 = {0,0,0,0}, acc1 = {0,0,0,0}, acc2 = {0,0,0,0};
  f32x4 acc3 = {0,0,0,0}, acc4 = {0,0,0,0}, acc5 = {0,0,0,0};
  f32x4 accO = {0,0,0,0};
  bf16x8 ones;
#pragma unroll
  for (int j = 0; j < 8; j++) ones[j] = (short)0x3F80;
  int p0 = chunk * 2048 + kg * 8;
  const bf16* arow = base + (((size_t)(ti * 16 + lr)) << 16);
#pragma unroll 2
  for (int s = 0; s < 64; s++) {
    int p = p0 + s * 32;
    bf16x8 fa = *(const bf16x8*)(arow + p);
    bf16x8 f0 = *(const bf16x8*)(base + (((size_t)(0 + lr)) << 16) + p);
    bf16x8 f1 = *(const bf16x8*)(base + (((size_t)(16 + lr)) << 16) + p);
    bf16x8 f2 = *(const bf16x8*)(base + (((size_t)(32 + lr)) << 16) + p);
    bf16x8 f3 = *(const bf16x8*)(base + (((size_t)(48 + lr)) << 16) + p);
    bf16x8 f4 = *(const bf16x8*)(base + (((size_t)(64 + lr)) << 16) + p);
    bf16x8 f5 = *(const bf16x8*)(base + (((size_t)(80 + lr)) << 16) + p);
    acc0 = __builtin_amdgcn_mfma_f32_16x16x32_bf16(fa, f0, acc0, 0, 0, 0);
    acc1 = __builtin_amdgcn_mfma_f32_16x16x32_bf16(fa, f1, acc1, 0, 0, 0);
    acc2 = __builtin_amdgcn_mfma_f32_16x16x32_bf16(fa, f2, acc2, 0, 0, 0);
    acc3 = __builtin_amdgcn_mfma_f32_16x16x32_bf16(fa, f3, acc3, 0, 0, 0);
    acc4 = __builtin_amdgcn_mfma_f32_16x16x32_bf16(fa, f4, acc4, 0, 0, 0);
    acc5 = __builtin_amdgcn_mfma_f32_16x16x32_bf16(fa, f5, acc5, 0, 0, 0);
    accO = __builtin_amdgcn_mfma_f32_16x16x32_bf16(fa, ones, accO, 0, 0, 0);
  }
  f32x4 accs[6] = {acc0, acc1, acc2, acc3, acc4, acc5};
#pragma unroll
  for (int t = 0; t < 6; t++)
#pragma unroll
    for (int r = 0; r < 4; r++) {
      int i = ti * 16 + kg * 4 + r, j = t * 16 + lr;
      atomicAdd(&G2[(size_t)(b * OC + i) * OC + j], accs[t][r]);
    }
#pragma unroll
  for (int r = 0; r < 4; r++) {
    int i = ti * 16 + kg * 4 + r;
    if (lr == 0) atomicAdd(&musum[b * OC + i], accO[r]);
  }
}

// ---------------- combine: per (b,oc) scale/shift for fused IN ----------------
__global__ void __launch_bounds__(128) k_statsF(const float* __restrict__ G2,
    const float* __restrict__ musum, const float* __restrict__ wf,
    const float* __restrict__ bfv, float* __restrict__ scale,
    float* __restrict__ shift) {
  int oc = blockIdx.x, b = blockIdx.y;
  int j = threadIdx.x;
  float quad = 0.f, lin = 0.f;
  if (j < OC) {
    float wj = __bfloat162float(__float2bfloat16(wf[oc * OC + j]));
    const float* g = G2 + (size_t)(b * OC) * OC + j;
    float inner = 0.f;
#pragma unroll 4
    for (int i = 0; i < OC; i++) {
      float wi = __bfloat162float(__float2bfloat16(wf[oc * OC + i]));
      inner = fmaf(wi, g[(size_t)i * OC], inner);
    }
    quad = wj * inner;
    lin = wj * musum[b * OC + j];
  }
  __shared__ float rq[2], rl[2];
  for (int off = 32; off > 0; off >>= 1) {
    quad += __shfl_down(quad, off);
    lin += __shfl_down(lin, off);
  }
  if ((threadIdx.x & 63) == 0) { rq[threadIdx.x >> 6] = quad; rl[threadIdx.x >> 6] = lin; }
  __syncthreads();
  if (threadIdx.x == 0) {
    float Q = rq[0] + rq[1], L = rl[0] + rl[1];
    const float invN = 1.f / 65536.f;
    float bias = bfv[oc];
    float mean = L * invN + bias;
    float e2 = Q * invN + 2.f * bias * (L * invN) + bias * bias;
    float var = e2 - mean * mean;
    float rstd = rsqrtf(fmaxf(var, 0.f) + EPS);
    scale[b * OC + oc] = rstd;
    shift[b * OC + oc] = (bias - mean) * rstd;
  }
}

// ---------------- fused final conv1x1 (MFMA) + IN + prelu -> d_out ------------------
// staging: p = it>>4 (channel pair), sub = it&15 -> 16-lane groups read 256B
// contiguous (coalesced); CROW=53 keeps LDS writes at 4-way, b128 reads clean.
constexpr int CROW = 53;
__global__ void __launch_bounds__(256) k_conv1x1f(const bf16* __restrict__ cat,
    const bf16* __restrict__ wbf, const float* __restrict__ scale,
    const float* __restrict__ shift, const float* __restrict__ af,
    float* __restrict__ out) {
  __shared__ unsigned int sT[128 * CROW];
  int b = blockIdx.x >> 6;
  int px0 = (blockIdx.x & 63) * 1024;
  int tid = threadIdx.x, w = tid >> 6, l = tid & 63;
  int lr = l & 15, kg = l >> 4;
  bf16x8 wf_[6][3];
#pragma unroll
  for (int t = 0; t < 6; t++)
#pragma unroll
    for (int ks = 0; ks < 3; ks++)
      wf_[t][ks] = *(const bf16x8*)(wbf + (t * 16 + lr) * OC + ks * 32 + kg * 8);
  float al = af[0];
  int bo = b * OC;
  const f32x4* scv = (const f32x4*)(scale + bo);
  const f32x4* shv = (const f32x4*)(shift + bo);
  const bf16* cb = cat + ((size_t)bo << 16);

  bf16x8 pa[3], pc_[3];
#define LOADR(RP0)                                                         \
  {                                                                        \
    _Pragma("unroll")                                                      \
    for (int k = 0; k < 3; k++) {                                          \
      int it = tid + k * 256;                                              \
      int p = it >> 4, sub = it & 15;                                      \
      const bf16* r0 = cb + (((size_t)(2 * p)) << 16) + (RP0) + sub * 8;   \
      pa[k] = *(const bf16x8*)r0;                                          \
      pc_[k] = *(const bf16x8*)(r0 + 65536);                               \
    }                                                                      \
  }
  LOADR(px0);
  for (int round = 0; round < 8; round++) {
    int rp0 = px0 + round * 128;
    __syncthreads();
#pragma unroll
    for (int k = 0; k < 3; k++) {
      int it = tid + k * 256;
      int p = it >> 4, sub = it & 15;
#pragma unroll
      for (int j = 0; j < 8; j++) {
        unsigned int d = (unsigned int)(unsigned short)pa[k][j]
                       | ((unsigned int)(unsigned short)pc_[k][j] << 16);
        sT[(sub * 8 + j) * CROW + p] = d;
      }
    }
    __syncthreads();
    if (round < 7) LOADR(px0 + (round + 1) * 128);
#pragma unroll
    for (int pt = 0; pt < 2; pt++) {
      int tloc = w * 2 + pt;
      int pl = tloc * 16 + lr;
      f32x4 a0 = {0,0,0,0}, a1 = {0,0,0,0}, a2 = {0,0,0,0};
      f32x4 a3 = {0,0,0,0}, a4 = {0,0,0,0}, a5 = {0,0,0,0};
#pragma unroll
      for (int ks = 0; ks < 3; ks++) {
        bf16x8 bf_ = *(const bf16x8*)&sT[pl * CROW + ks * 16 + kg * 4];
        a0 = __builtin_amdgcn_mfma_f32_16x16x32_bf16(wf_[0][ks], bf_, a0, 0, 0, 0);
        a1 = __builtin_amdgcn_mfma_f32_16x16x32_bf16(wf_[1][ks], bf_, a1, 0, 0, 0);
        a2 = __builtin_amdgcn_mfma_f32_16x16x32_bf16(wf_[2][ks], bf_, a2, 0, 0, 0);
        a3 = __builtin_amdgcn_mfma_f32_16x16x32_bf16(wf_[3][ks], bf_, a3, 0, 0, 0);
        a4 = __builtin_amdgcn_mfma_f32_16x16x32_bf16(wf_[4][ks], bf_, a4, 0, 0, 0);
        a5 = __builtin_amdgcn_mfma_f32_16x16x32_bf16(wf_[5][ks], bf_, a5, 0, 0, 0);
      }
      f32x4 accs[6] = {a0, a1, a2, a3, a4, a5};
      int px = rp0 + tloc * 16 + lr;
#pragma unroll
      for (int t = 0; t < 6; t++) {
        f32x4 sc4 = scv[t * 4 + kg];
        f32x4 sh4 = shv[t * 4 + kg];
#pragma unroll
        for (int r = 0; r < 4; r++) {
          int oc = t * 16 + kg * 4 + r;
          float v = accs[t][r] * sc4[r] + sh4[r];
          v = v >= 0.f ? v : al * v;
          out[((size_t)(bo + oc) << 16) + px] = v;
        }
      }
    }
  }
#undef LOADR
}

extern "C" void kernel_launch(void* const* d_in, const int* in_sizes, int n_in,
                              void* d_out, int out_size, void* d_ws, size_t ws_size,
                              hipStream_t stream) {
  const float* x   = (const float*)d_in[0];
  const float* w[3]  = {(const float*)d_in[1], (const float*)d_in[4], (const float*)d_in[7]};
  const float* bb[3] = {(const float*)d_in[2], (const float*)d_in[5], (const float*)d_in[8]};
  const float* aa[3] = {(const float*)d_in[3], (const float*)d_in[6], (const float*)d_in[9]};
  const float* wfp = (const float*)d_in[10];
  const float* bfv = (const float*)d_in[11];
  const float* af  = (const float*)d_in[12];
  float* out = (float*)d_out;

  // workspace: cat bf16 201MB | fraw bf16 88MB | cur1 | cur2 | sacc | wA3 | G2 |
  //            musum | scale | shift | wbf
  char* ws = (char*)d_ws;
  bf16*  cat  = (bf16*)ws;
  bf16*  fraw = (bf16*)(ws + 201326592ull);
  float* cur1 = (float*)(ws + 201326592ull + FR_TOT * 2ull);
  float* cur2 = cur1 + 786432;
  float* sacc = cur2 + 196608;
  bf16*  wA3  = (bf16*)(sacc + 3072);
  float* G2   = (float*)(wA3 + 15360);
  float* musum = G2 + 147456;
  float* scale = musum + 1536;
  float* shift = scale + 1536;
  bf16*  wbf   = (bf16*)(shift + 1536);

  auto cdiv = [](int a, int b) { return (a + b - 1) / b; };

  k_prep<<<582, 256, 0, stream>>>(w[0], w[1], w[2], wfp, sacc, G2, wA3, wbf);
  k_avgpool_b<<<cdiv(B * CIN * 64 * 64, 256), 256, 0, stream>>>(x, cur1, cur2);

  dim3 g3(84, B);
  k_fused3m<<<g3, 256, 0, stream>>>(x, cur1, cur2, wA3, bb[0], bb[1], bb[2],
                                    fraw, sacc);
  k_normcat<<<cdiv(B * OC * H * W / 8, 256), 256, 0, stream>>>(fraw, sacc, aa[0],
                                                               aa[1], aa[2], cat);
  k_moments<<<16 * 32, 384, 0, stream>>>(cat, G2, musum);
  dim3 gs(OC, B);
  k_statsF<<<gs, 128, 0, stream>>>(G2, musum, wfp, bfv, scale, shift);
  k_conv1x1f<<<16 * 64, 256, 0, stream>>>(cat, wbf, scale, shift, af, out);
}

// Round 9
// 521.187 us; speedup vs baseline: 4.1598x; 1.1738x over previous
//
#include <hip/hip_runtime.h>
#include <hip/hip_bf16.h>

typedef __hip_bfloat16 bf16;
typedef __attribute__((ext_vector_type(8))) short bf16x8;
typedef __attribute__((ext_vector_type(4))) float f32x4;
typedef __attribute__((ext_vector_type(2))) float f32x2;

constexpr int B = 16, CIN = 3, OPL = 32, OC = 96, H = 256, W = 256;
#define EPS 1e-5f

// fraw level offsets (elements)
constexpr size_t FR_L1 = 33554432ull;
constexpr size_t FR_L2 = 41943040ull;
constexpr size_t FR_TOT = 44040192ull;

// ---------------- prep: zero accumulators + convert/pack all weights ----------------
__global__ void k_prep(const float* __restrict__ w0, const float* __restrict__ w1,
                       const float* __restrict__ w2, const float* __restrict__ wf,
                       float* __restrict__ sacc, float* __restrict__ G2zone,
                       bf16* __restrict__ wA, bf16* __restrict__ wbf) {
  int i = blockIdx.x * 256 + threadIdx.x;
  if (i < 3072) sacc[i] = 0.f;
  if (i < 147456 + 1536) G2zone[i] = 0.f;          // G2 + musum
  if (i < OC * OC) wbf[i] = __float2bfloat16(wf[i]);
  if (i < 3 * 5120) {
    int l = i / 5120, rem = i % 5120;
    int entry = rem >> 5, kk = rem & 31;
    int r = entry >> 5, g = (entry >> 4) & 1, lr = entry & 15;
    int t2 = kk >> 4, ic = kk & 15;
    int tap = 2 * r + t2;
    const float* wl = l == 0 ? w0 : (l == 1 ? w1 : w2);
    float v = 0.f;
    if (tap <= 8 && ic < 12) v = wl[((g * 16 + lr) * 12 + ic) * 9 + tap];
    wA[i] = __float2bfloat16(v);
  }
}

// ---------------- avg pool: both levels in one kernel ----------------
__global__ void k_avgpool_b(const float* __restrict__ x, float* __restrict__ cur1,
                            float* __restrict__ cur2) {
  int n = B * CIN * 64 * 64;
  int t = blockIdx.x * blockDim.x + threadIdx.x;
  if (t >= n) return;
  int xx = t & 63, y = (t >> 6) & 63, p = t >> 12;
  const float* ip = x + (size_t)p * 65536 + (size_t)(4 * y) * 256 + 4 * xx;
  f32x4 r0 = *(const f32x4*)ip;
  f32x4 r1 = *(const f32x4*)(ip + 256);
  f32x4 r2 = *(const f32x4*)(ip + 512);
  f32x4 r3 = *(const f32x4*)(ip + 768);
  f32x2 c1a, c1b;
  c1a[0] = 0.25f * (r0[0] + r0[1] + r1[0] + r1[1]);
  c1a[1] = 0.25f * (r0[2] + r0[3] + r1[2] + r1[3]);
  c1b[0] = 0.25f * (r2[0] + r2[1] + r3[0] + r3[1]);
  c1b[1] = 0.25f * (r2[2] + r2[3] + r3[2] + r3[3]);
  float* c1p = cur1 + (size_t)p * 16384 + (size_t)(2 * y) * 128 + 2 * xx;
  *(f32x2*)c1p = c1a;
  *(f32x2*)(c1p + 128) = c1b;
  cur2[(size_t)p * 4096 + (size_t)y * 64 + xx] =
      0.25f * (c1a[0] + c1a[1] + c1b[0] + c1b[1]);
}

// ---------------- FUSED: Haar + bilinear-up + conv3x3 (MFMA) + stats, 3 levels ------
__global__ void __launch_bounds__(256) k_fused3m(const float* __restrict__ x,
    const float* __restrict__ cur1, const float* __restrict__ cur2,
    const bf16* __restrict__ wA3,
    const float* __restrict__ b0, const float* __restrict__ b1,
    const float* __restrict__ b2,
    bf16* __restrict__ fraw, float* __restrict__ sacc) {
  __shared__ unsigned int sPool[34 * 34 * 12 + 18 * 18 * 12];
  unsigned int* sInT = sPool;
  float* sCur = (float*)sPool;
  float* sBands = (float*)(sPool + 34 * 34 * 12);

  int bxid = blockIdx.x, b = blockIdx.y;
  int lvl, tile, Hl, ntx;
  const float* cur; const float* bias; bf16* frawL;
  if (bxid < 64)      { lvl = 0; tile = bxid;      Hl = 256; ntx = 8; cur = x;    bias = b0; frawL = fraw; }
  else if (bxid < 80) { lvl = 1; tile = bxid - 64; Hl = 128; ntx = 4; cur = cur1; bias = b1; frawL = fraw + FR_L1; }
  else                { lvl = 2; tile = bxid - 80; Hl = 64;  ntx = 2; cur = cur2; bias = b2; frawL = fraw + FR_L2; }
  const bf16* wA = wA3 + lvl * 5120;
  float* saccL = sacc + lvl * 1024;

  int by = (tile / ntx) * 32, bx = (tile % ntx) * 32;
  int tid = threadIdx.x;
  int h2 = Hl >> 1;
  size_t plane = (size_t)Hl * Hl;

  int w = tid >> 6, l = tid & 63;
  int lr = l & 15, kg = l >> 4;
  int yloc = (w >> 1) * 16, xloc = (w & 1) * 16;
  bf16x8 wf_[5][2];
#pragma unroll
  for (int r = 0; r < 5; r++)
#pragma unroll
    for (int g = 0; g < 2; g++)
      wf_[r][g] = *(const bf16x8*)(wA + ((r * 2 + g) * 16 + lr) * 32 + kg * 8);
  int offr[5];
#pragma unroll
  for (int r = 0; r < 5; r++) {
    int tap = 2 * r + (kg >> 1);
    if (tap > 8) tap = 8;
    int dy = tap / 3 - 1, dx = tap - (tap / 3) * 3 - 1;
    offr[r] = (dy * 34 + dx) * 12 + (kg & 1) * 4;
  }
  float bi[2][4];
#pragma unroll
  for (int g = 0; g < 2; g++)
#pragma unroll
    for (int rg = 0; rg < 4; rg++)
      bi[g][rg] = bias[g * 16 + kg * 4 + rg];

  // phase A: load cur tile, clamped
  const float* cb = cur + (size_t)(b * CIN) * plane;
  for (int it = tid; it < 3 * 36 * 36; it += 256) {
    int xx = it % 36, rest = it / 36, yy = rest % 36, c = rest / 36;
    int gy = by - 2 + yy, gx = bx - 2 + xx;
    gy = gy < 0 ? 0 : (gy > Hl - 1 ? Hl - 1 : gy);
    gx = gx < 0 ? 0 : (gx > Hl - 1 ? Hl - 1 : gx);
    sCur[it] = cb[c * plane + (size_t)gy * Hl + gx];
  }
  __syncthreads();

  // phase B: Haar bands 18x18
  for (int it = tid; it < 18 * 18 * 3; it += 256) {
    int c = it % 3, rest = it / 3, xs = rest % 18, ys = rest / 18;
    const float* cp = sCur + c * 1296 + (2 * ys) * 36 + 2 * xs;
    float e = cp[0], f = cp[1], g = cp[36], h = cp[37];
    f32x4 v;
    v[0] = (e + f + g + h) * 0.5f;
    v[1] = (e + f - g - h) * 0.5f;
    v[2] = (e - f + g - h) * 0.5f;
    v[3] = (e - f - g + h) * 0.5f;
    *(f32x4*)&sBands[(ys * 18 + xs) * 12 + c * 4] = v;
  }
  __syncthreads();

  // phase C: bilinear x2 expand into packed sInT
  int yb_base = (by >> 1) - 1, xb_base = (bx >> 1) - 1;
  for (int it = tid; it < 34 * 34 * 3; it += 256) {
    int c = it % 3, rest = it / 3, xx = rest % 34, yy = rest / 34;
    int base = (yy * 34 + xx) * 12 + c * 2;
    int Y = by - 1 + yy, X = bx - 1 + xx;
    if (Y < 0 || Y >= Hl || X < 0 || X >= Hl) {
      sInT[base] = 0; sInT[base + 1] = 0;
      continue;
    }
    int my = Y >> 1, dy = Y & 1;
    int y0 = my - 1 + dy;
    float wy = dy ? 0.25f : 0.75f;
    int y0c = y0 < 0 ? 0 : y0, y1c = (y0 + 1 > h2 - 1) ? h2 - 1 : y0 + 1;
    int ys0 = y0c - yb_base, ys1 = y1c - yb_base;
    int mx = X >> 1, dx = X & 1;
    int x0 = mx - 1 + dx;
    float wx = dx ? 0.25f : 0.75f;
    int x0c = x0 < 0 ? 0 : x0, x1c = (x0 + 1 > h2 - 1) ? h2 - 1 : x0 + 1;
    int xs0 = x0c - xb_base, xs1 = x1c - xb_base;
    f32x4 c00 = *(const f32x4*)&sBands[(ys0 * 18 + xs0) * 12 + c * 4];
    f32x4 c01 = *(const f32x4*)&sBands[(ys0 * 18 + xs1) * 12 + c * 4];
    f32x4 c10 = *(const f32x4*)&sBands[(ys1 * 18 + xs0) * 12 + c * 4];
    f32x4 c11 = *(const f32x4*)&sBands[(ys1 * 18 + xs1) * 12 + c * 4];
    f32x4 v0 = c00 + wx * (c01 - c00);
    f32x4 v1 = c10 + wx * (c11 - c10);
    f32x4 v = v0 + wy * (v1 - v0);
    unsigned int d0 = (unsigned int)__bfloat16_as_ushort(__float2bfloat16(v[0]))
                    | ((unsigned int)__bfloat16_as_ushort(__float2bfloat16(v[1])) << 16);
    unsigned int d1 = (unsigned int)__bfloat16_as_ushort(__float2bfloat16(v[2]))
                    | ((unsigned int)__bfloat16_as_ushort(__float2bfloat16(v[3])) << 16);
    sInT[base] = d0;
    sInT[base + 1] = d1;
  }
  for (int it = tid; it < 34 * 34; it += 256) {
    sInT[it * 12 + 6] = 0;
    sInT[it * 12 + 7] = 0;
  }
  __syncthreads();

  // MFMA conv + bf16 store + fused stats
  float s_[2][4], s2_[2][4];
#pragma unroll
  for (int g = 0; g < 2; g++)
#pragma unroll
    for (int rg = 0; rg < 4; rg++) { s_[g][rg] = 0.f; s2_[g][rg] = 0.f; }

  bf16* frb = frawL + (size_t)b * OPL * plane;
  for (int y = 0; y < 16; y++) {
    int rowbase = ((yloc + y + 1) * 34 + (xloc + lr + 1)) * 12;
    f32x4 a0 = {0, 0, 0, 0}, a1 = {0, 0, 0, 0};
#pragma unroll
    for (int r = 0; r < 5; r++) {
      bf16x8 bf_ = *(const bf16x8*)&sInT[rowbase + offr[r]];
      a0 = __builtin_amdgcn_mfma_f32_16x16x32_bf16(wf_[r][0], bf_, a0, 0, 0, 0);
      a1 = __builtin_amdgcn_mfma_f32_16x16x32_bf16(wf_[r][1], bf_, a1, 0, 0, 0);
    }
    int gy = by + yloc + y, gxp = bx + xloc + lr;
    size_t po = (size_t)gy * Hl + gxp;
#pragma unroll
    for (int rg = 0; rg < 4; rg++) {
      bf16 vb0 = __float2bfloat16(a0[rg] + bi[0][rg]);
      bf16 vb1 = __float2bfloat16(a1[rg] + bi[1][rg]);
      frb[(size_t)(kg * 4 + rg) * plane + po] = vb0;
      frb[(size_t)(16 + kg * 4 + rg) * plane + po] = vb1;
      float v0 = __bfloat162float(vb0), v1 = __bfloat162float(vb1);
      s_[0][rg] += v0; s2_[0][rg] += v0 * v0;
      s_[1][rg] += v1; s2_[1][rg] += v1 * v1;
    }
  }
#pragma unroll
  for (int g = 0; g < 2; g++)
#pragma unroll
    for (int rg = 0; rg < 4; rg++) {
      float s = s_[g][rg], s2 = s2_[g][rg];
#pragma unroll
      for (int m = 8; m >= 1; m >>= 1) {
        s += __shfl_xor(s, m);
        s2 += __shfl_xor(s2, m);
      }
      if (lr == 0) {
        int pc = b * OPL + g * 16 + kg * 4 + rg;
        atomicAdd(&saccL[pc * 2], s);
        atomicAdd(&saccL[pc * 2 + 1], s2);
      }
    }
}

// ---------------- shared transform: 8 px of channel ch at row y, cols x0..x0+7 ------
// (validated in R7: correctness passed; only the old lane decomposition was slow)
__device__ inline void cat_row8(const bf16* __restrict__ fraw,
    const float* __restrict__ sacc, const float* __restrict__ a0,
    const float* __restrict__ a1, const float* __restrict__ a2,
    int b, int ch, int y, int x0, bf16x8* out8) {
  int lvl = ch < 32 ? 0 : (ch < 64 ? 1 : 2);
  int cl = ch - 32 * lvl;
  int pcl = b * 32 + cl;
  const float* sl = sacc + lvl * 1024;
  float invN = lvl == 0 ? (1.f / 65536.f) : (lvl == 1 ? (1.f / 16384.f) : (1.f / 4096.f));
  float mean = sl[pcl * 2] * invN;
  float var = sl[pcl * 2 + 1] * invN - mean * mean;
  float rstd = rsqrtf(fmaxf(var, 0.f) + EPS);
  float al = lvl == 0 ? a0[0] : (lvl == 1 ? a1[0] : a2[0]);
  bf16x8 o;
  if (lvl == 0) {
    bf16x8 in = *(const bf16x8*)(fraw + (((size_t)pcl) << 16) + y * 256 + x0);
#pragma unroll
    for (int j = 0; j < 8; j++) {
      float v = __bfloat162float(__ushort_as_bfloat16((unsigned short)in[j]));
      v = (v - mean) * rstd;
      v = v >= 0.f ? v : al * v;
      o[j] = (short)__bfloat16_as_ushort(__float2bfloat16(v));
    }
  } else {
    int n = lvl == 1 ? 128 : 64;
    size_t lvloff = lvl == 1 ? FR_L1 : FR_L2;
    int shift = lvl == 1 ? 14 : 12;
    const bf16* ip = fraw + lvloff + (((size_t)pcl) << shift);
    int y0; float wy;
    if (lvl == 1) { int d = y & 1; y0 = (y >> 1) - 1 + d; wy = d ? 0.25f : 0.75f; }
    else {
      int d = y & 3; y0 = (y >> 2) - 1 + (d >> 1);
      wy = (d & 1) ? ((d >> 1) ? 0.375f : 0.875f) : ((d >> 1) ? 0.125f : 0.625f);
    }
    int y0c = y0 < 0 ? 0 : y0;
    int y1c = (y0 + 1 > n - 1) ? n - 1 : y0 + 1;
    const bf16* r0p = ip + (size_t)y0c * n;
    const bf16* r1p = ip + (size_t)y1c * n;
#pragma unroll
    for (int j = 0; j < 8; j++) {
      int xx = x0 + j;
      int xi; float wx;
      if (lvl == 1) { int d = xx & 1; xi = (xx >> 1) - 1 + d; wx = d ? 0.25f : 0.75f; }
      else {
        int d = xx & 3; xi = (xx >> 2) - 1 + (d >> 1);
        wx = (d & 1) ? ((d >> 1) ? 0.375f : 0.875f) : ((d >> 1) ? 0.125f : 0.625f);
      }
      int x0c = xi < 0 ? 0 : xi;
      int x1c = (xi + 1 > n - 1) ? n - 1 : xi + 1;
      float v00 = __bfloat162float(r0p[x0c]);
      float v01 = __bfloat162float(r0p[x1c]);
      float v10 = __bfloat162float(r1p[x0c]);
      float v11 = __bfloat162float(r1p[x1c]);
      v00 = (v00 - mean) * rstd; v00 = v00 >= 0.f ? v00 : al * v00;
      v01 = (v01 - mean) * rstd; v01 = v01 >= 0.f ? v01 : al * v01;
      v10 = (v10 - mean) * rstd; v10 = v10 >= 0.f ? v10 : al * v10;
      v11 = (v11 - mean) * rstd; v11 = v11 >= 0.f ? v11 : al * v11;
      float v = (1.f - wy) * ((1.f - wx) * v00 + wx * v01)
              + wy * ((1.f - wx) * v10 + wx * v11);
      o[j] = (short)__bfloat16_as_ushort(__float2bfloat16(v));
    }
  }
  *out8 = o;
}

// ---------------- FUSED normcat + moments: transform -> {cat, LDS} -> G2/musum ------
// grid: 16 b x 32 chunks (8 rows of 256 px); 384 thr; LDS 96 x 268 shorts (51.5 KB).
// Staging decomposition: ch = u>>5 (32 consecutive threads cover 256 px of ONE
// channel) -> coalesced fraw reads (l0) + coalesced cat writes. Validated in normcat.
constexpr int MROW = 268;   // stride: 134 dw -> 16 row-lanes hit distinct banks
__global__ void __launch_bounds__(384) k_normmom(const bf16* __restrict__ fraw,
    const float* __restrict__ sacc, const float* __restrict__ a0,
    const float* __restrict__ a1, const float* __restrict__ a2,
    bf16* __restrict__ cat, float* __restrict__ G2, float* __restrict__ musum) {
  __shared__ short sV[96 * MROW];
  int b = blockIdx.x >> 5, chunk = blockIdx.x & 31;
  int tid = threadIdx.x;
  int ti = tid >> 6, l = tid & 63, lr = l & 15, kg = l >> 4;
  f32x4 acc0 = {0,0,0,0}, acc1 = {0,0,0,0}, acc2 = {0,0,0,0};
  f32x4 acc3 = {0,0,0,0}, acc4 = {0,0,0,0}, acc5 = {0,0,0,0};
  f32x4 accO = {0,0,0,0};
  bf16x8 ones;
#pragma unroll
  for (int j = 0; j < 8; j++) ones[j] = (short)0x3F80;

  for (int sub = 0; sub < 8; sub++) {
    int y = chunk * 8 + sub;
    __syncthreads();
    // stage-transform 96 ch x 256 px; also write cat (both coalesced)
#pragma unroll
    for (int a = 0; a < 8; a++) {
      int u = tid + a * 384;
      int ch = u >> 5, grp = u & 31;
      bf16x8 o8;
      cat_row8(fraw, sacc, a0, a1, a2, b, ch, y, grp * 8, &o8);
      *(bf16x8*)&sV[ch * MROW + grp * 8] = o8;
      *(bf16x8*)(cat + (((size_t)(b * OC + ch)) << 16) + y * 256 + grp * 8) = o8;
    }
    __syncthreads();
    // G2 MFMA over 8 K-steps of 32 px
#pragma unroll
    for (int s = 0; s < 8; s++) {
      int po = s * 32 + kg * 8;
      bf16x8 fa = *(const bf16x8*)&sV[(ti * 16 + lr) * MROW + po];
      bf16x8 f0 = *(const bf16x8*)&sV[(0 * 16 + lr) * MROW + po];
      bf16x8 f1 = *(const bf16x8*)&sV[(1 * 16 + lr) * MROW + po];
      bf16x8 f2 = *(const bf16x8*)&sV[(2 * 16 + lr) * MROW + po];
      bf16x8 f3 = *(const bf16x8*)&sV[(3 * 16 + lr) * MROW + po];
      bf16x8 f4 = *(const bf16x8*)&sV[(4 * 16 + lr) * MROW + po];
      bf16x8 f5 = *(const bf16x8*)&sV[(5 * 16 + lr) * MROW + po];
      acc0 = __builtin_amdgcn_mfma_f32_16x16x32_bf16(fa, f0, acc0, 0, 0, 0);
      acc1 = __builtin_amdgcn_mfma_f32_16x16x32_bf16(fa, f1, acc1, 0, 0, 0);
      acc2 = __builtin_amdgcn_mfma_f32_16x16x32_bf16(fa, f2, acc2, 0, 0, 0);
      acc3 = __builtin_amdgcn_mfma_f32_16x16x32_bf16(fa, f3, acc3, 0, 0, 0);
      acc4 = __builtin_amdgcn_mfma_f32_16x16x32_bf16(fa, f4, acc4, 0, 0, 0);
      acc5 = __builtin_amdgcn_mfma_f32_16x16x32_bf16(fa, f5, acc5, 0, 0, 0);
      accO = __builtin_amdgcn_mfma_f32_16x16x32_bf16(fa, ones, accO, 0, 0, 0);
    }
  }
  f32x4 accs[6] = {acc0, acc1, acc2, acc3, acc4, acc5};
#pragma unroll
  for (int t = 0; t < 6; t++)
#pragma unroll
    for (int r = 0; r < 4; r++) {
      int i = ti * 16 + kg * 4 + r, j = t * 16 + lr;
      atomicAdd(&G2[(size_t)(b * OC + i) * OC + j], accs[t][r]);
    }
#pragma unroll
  for (int r = 0; r < 4; r++) {
    int i = ti * 16 + kg * 4 + r;
    if (lr == 0) atomicAdd(&musum[b * OC + i], accO[r]);
  }
}

// ---------------- combine: per (b,oc) scale/shift for fused IN ----------------
__global__ void __launch_bounds__(128) k_statsF(const float* __restrict__ G2,
    const float* __restrict__ musum, const float* __restrict__ wf,
    const float* __restrict__ bfv, float* __restrict__ scale,
    float* __restrict__ shift) {
  int oc = blockIdx.x, b = blockIdx.y;
  int j = threadIdx.x;
  float quad = 0.f, lin = 0.f;
  if (j < OC) {
    float wj = __bfloat162float(__float2bfloat16(wf[oc * OC + j]));
    const float* g = G2 + (size_t)(b * OC) * OC + j;
    float inner = 0.f;
#pragma unroll 4
    for (int i = 0; i < OC; i++) {
      float wi = __bfloat162float(__float2bfloat16(wf[oc * OC + i]));
      inner = fmaf(wi, g[(size_t)i * OC], inner);
    }
    quad = wj * inner;
    lin = wj * musum[b * OC + j];
  }
  __shared__ float rq[2], rl[2];
  for (int off = 32; off > 0; off >>= 1) {
    quad += __shfl_down(quad, off);
    lin += __shfl_down(lin, off);
  }
  if ((threadIdx.x & 63) == 0) { rq[threadIdx.x >> 6] = quad; rl[threadIdx.x >> 6] = lin; }
  __syncthreads();
  if (threadIdx.x == 0) {
    float Q = rq[0] + rq[1], L = rl[0] + rl[1];
    const float invN = 1.f / 65536.f;
    float bias = bfv[oc];
    float mean = L * invN + bias;
    float e2 = Q * invN + 2.f * bias * (L * invN) + bias * bias;
    float var = e2 - mean * mean;
    float rstd = rsqrtf(fmaxf(var, 0.f) + EPS);
    scale[b * OC + oc] = rstd;
    shift[b * OC + oc] = (bias - mean) * rstd;
  }
}

// ---------------- fused final conv1x1 (MFMA) + IN + prelu -> d_out ------------------
constexpr int CROW = 53;
__global__ void __launch_bounds__(256) k_conv1x1f(const bf16* __restrict__ cat,
    const bf16* __restrict__ wbf, const float* __restrict__ scale,
    const float* __restrict__ shift, const float* __restrict__ af,
    float* __restrict__ out) {
  __shared__ unsigned int sT[128 * CROW];
  int b = blockIdx.x >> 6;
  int px0 = (blockIdx.x & 63) * 1024;
  int tid = threadIdx.x, w = tid >> 6, l = tid & 63;
  int lr = l & 15, kg = l >> 4;
  bf16x8 wf_[6][3];
#pragma unroll
  for (int t = 0; t < 6; t++)
#pragma unroll
    for (int ks = 0; ks < 3; ks++)
      wf_[t][ks] = *(const bf16x8*)(wbf + (t * 16 + lr) * OC + ks * 32 + kg * 8);
  float al = af[0];
  int bo = b * OC;
  const f32x4* scv = (const f32x4*)(scale + bo);
  const f32x4* shv = (const f32x4*)(shift + bo);
  const bf16* cb = cat + ((size_t)bo << 16);

  bf16x8 pa[3], pc_[3];
#define LOADR(RP0)                                                         \
  {                                                                        \
    _Pragma("unroll")                                                      \
    for (int k = 0; k < 3; k++) {                                          \
      int it = tid + k * 256;                                              \
      int p = it >> 4, sub = it & 15;                                      \
      const bf16* r0 = cb + (((size_t)(2 * p)) << 16) + (RP0) + sub * 8;   \
      pa[k] = *(const bf16x8*)r0;                                          \
      pc_[k] = *(const bf16x8*)(r0 + 65536);                               \
    }                                                                      \
  }
  LOADR(px0);
  for (int round = 0; round < 8; round++) {
    int rp0 = px0 + round * 128;
    __syncthreads();
#pragma unroll
    for (int k = 0; k < 3; k++) {
      int it = tid + k * 256;
      int p = it >> 4, sub = it & 15;
#pragma unroll
      for (int j = 0; j < 8; j++) {
        unsigned int d = (unsigned int)(unsigned short)pa[k][j]
                       | ((unsigned int)(unsigned short)pc_[k][j] << 16);
        sT[(sub * 8 + j) * CROW + p] = d;
      }
    }
    __syncthreads();
    if (round < 7) LOADR(px0 + (round + 1) * 128);
#pragma unroll
    for (int pt = 0; pt < 2; pt++) {
      int tloc = w * 2 + pt;
      int pl = tloc * 16 + lr;
      f32x4 a0 = {0,0,0,0}, a1 = {0,0,0,0}, a2 = {0,0,0,0};
      f32x4 a3 = {0,0,0,0}, a4 = {0,0,0,0}, a5 = {0,0,0,0};
#pragma unroll
      for (int ks = 0; ks < 3; ks++) {
        bf16x8 bf_ = *(const bf16x8*)&sT[pl * CROW + ks * 16 + kg * 4];
        a0 = __builtin_amdgcn_mfma_f32_16x16x32_bf16(wf_[0][ks], bf_, a0, 0, 0, 0);
        a1 = __builtin_amdgcn_mfma_f32_16x16x32_bf16(wf_[1][ks], bf_, a1, 0, 0, 0);
        a2 = __builtin_amdgcn_mfma_f32_16x16x32_bf16(wf_[2][ks], bf_, a2, 0, 0, 0);
        a3 = __builtin_amdgcn_mfma_f32_16x16x32_bf16(wf_[3][ks], bf_, a3, 0, 0, 0);
        a4 = __builtin_amdgcn_mfma_f32_16x16x32_bf16(wf_[4][ks], bf_, a4, 0, 0, 0);
        a5 = __builtin_amdgcn_mfma_f32_16x16x32_bf16(wf_[5][ks], bf_, a5, 0, 0, 0);
      }
      f32x4 accs[6] = {a0, a1, a2, a3, a4, a5};
      int px = rp0 + tloc * 16 + lr;
#pragma unroll
      for (int t = 0; t < 6; t++) {
        f32x4 sc4 = scv[t * 4 + kg];
        f32x4 sh4 = shv[t * 4 + kg];
#pragma unroll
        for (int r = 0; r < 4; r++) {
          int oc = t * 16 + kg * 4 + r;
          float v = accs[t][r] * sc4[r] + sh4[r];
          v = v >= 0.f ? v : al * v;
          out[((size_t)(bo + oc) << 16) + px] = v;
        }
      }
    }
  }
#undef LOADR
}

extern "C" void kernel_launch(void* const* d_in, const int* in_sizes, int n_in,
                              void* d_out, int out_size, void* d_ws, size_t ws_size,
                              hipStream_t stream) {
  const float* x   = (const float*)d_in[0];
  const float* w[3]  = {(const float*)d_in[1], (const float*)d_in[4], (const float*)d_in[7]};
  const float* bb[3] = {(const float*)d_in[2], (const float*)d_in[5], (const float*)d_in[8]};
  const float* aa[3] = {(const float*)d_in[3], (const float*)d_in[6], (const float*)d_in[9]};
  const float* wfp = (const float*)d_in[10];
  const float* bfv = (const float*)d_in[11];
  const float* af  = (const float*)d_in[12];
  float* out = (float*)d_out;

  // workspace: cat bf16 201MB | fraw bf16 88MB | cur1 | cur2 | sacc | wA3 | G2 |
  //            musum | scale | shift | wbf
  char* ws = (char*)d_ws;
  bf16*  cat  = (bf16*)ws;
  bf16*  fraw = (bf16*)(ws + 201326592ull);
  float* cur1 = (float*)(ws + 201326592ull + FR_TOT * 2ull);
  float* cur2 = cur1 + 786432;
  float* sacc = cur2 + 196608;
  bf16*  wA3  = (bf16*)(sacc + 3072);
  float* G2   = (float*)(wA3 + 15360);
  float* musum = G2 + 147456;
  float* scale = musum + 1536;
  float* shift = scale + 1536;
  bf16*  wbf   = (bf16*)(shift + 1536);

  auto cdiv = [](int a, int b) { return (a + b - 1) / b; };

  k_prep<<<582, 256, 0, stream>>>(w[0], w[1], w[2], wfp, sacc, G2, wA3, wbf);
  k_avgpool_b<<<cdiv(B * CIN * 64 * 64, 256), 256, 0, stream>>>(x, cur1, cur2);

  dim3 g3(84, B);
  k_fused3m<<<g3, 256, 0, stream>>>(x, cur1, cur2, wA3, bb[0], bb[1], bb[2],
                                    fraw, sacc);
  k_normmom<<<16 * 32, 384, 0, stream>>>(fraw, sacc, aa[0], aa[1], aa[2],
                                         cat, G2, musum);
  dim3 gs(OC, B);
  k_statsF<<<gs, 128, 0, stream>>>(G2, musum, wfp, bfv, scale, shift);
  k_conv1x1f<<<16 * 64, 256, 0, stream>>>(cat, wbf, scale, shift, af, out);
}